// Round 1
// baseline (902.943 us; speedup 1.0000x reference)
//
#include <hip/hip_runtime.h>
#include <math.h>

// Problem constants: B=4, CG=384, CY=2, H=W=224, CH=32
#define HW2 50176            // 224*224
#define NPLANE 6422528       // 4*32*224*224  (one [B,32,H,W] tensor)

// ---------------------------------------------------------------------------
// conv_end_3: [4,2,224,224] -> [4,32,224,224], 3x3 same, no bias
// ---------------------------------------------------------------------------
__global__ __launch_bounds__(256) void conv3_kernel(const float* __restrict__ y,
                                                    const float* __restrict__ w3,
                                                    float* __restrict__ y32)
{
    int idx = blockIdx.x * 256 + threadIdx.x;
    if (idx >= NPLANE) return;
    int w  = idx % 224;
    int h  = (idx / 224) % 224;
    int co = (idx / HW2) % 32;
    int b  = idx / (HW2 * 32);
    const float* yb = y + (size_t)b * 2 * HW2;
    float acc = 0.f;
#pragma unroll
    for (int ci = 0; ci < 2; ci++) {
#pragma unroll
        for (int kh = 0; kh < 3; kh++) {
            int hy = h + kh - 1;
            if (hy < 0 || hy > 223) continue;
#pragma unroll
            for (int kw = 0; kw < 3; kw++) {
                int wy = w + kw - 1;
                if (wy < 0 || wy > 223) continue;
                acc += yb[ci * HW2 + hy * 224 + wy] * w3[((co * 2 + ci) * 3 + kh) * 3 + kw];
            }
        }
    }
    y32[idx] = acc;
}

// ---------------------------------------------------------------------------
// Gated recurrent scan.  h_t[s] = x + (g1*(h[s-1]-x) + g2*(h[s]-x) + g3*(h[s+1]-x))/den
// with den = max(|g1|+|g2|+|g3|, 1).  Algebraically identical to
// (1-a1-a2-a3)*x + a1*hu + a2*hc + a3*hd with ai = gi/den.
// ---------------------------------------------------------------------------
__device__ __forceinline__ float gstep(float a1, float a2, float a3, float xv,
                                       float hu, float hc, float hd)
{
    float den = fabsf(a1) + fabsf(a2) + fabsf(a3);
    den = fmaxf(den, 1.0f);
    return xv + (a1 * (hu - xv) + a2 * (hc - xv) + a3 * (hd - xv)) / den;
}

// Vertical scan: t over H (rows), neighbor coupling along W. Thread s = column.
// Row loads are naturally coalesced. One-step register prefetch.
template <bool REV>
__device__ void scan_vert(const float* __restrict__ g1, const float* __restrict__ g2,
                          const float* __restrict__ g3, const float* __restrict__ xp,
                          float* __restrict__ op, int s, float* hA, float* hB)
{
    int off = (REV ? 223 * 224 : 0) + s;
    float a1 = g1[off], a2 = g2[off], a3 = g3[off], xv = xp[off];
    float* hp = hA;
    float* hn = hB;
    for (int i = 0; i < 224; i++) {
        int offn = off + (REV ? -224 : 224);
        float b1 = 0.f, b2 = 0.f, b3 = 0.f, bx = 0.f;
        if (i < 223) { b1 = g1[offn]; b2 = g2[offn]; b3 = g3[offn]; bx = xp[offn]; }
        float hv = gstep(a1, a2, a3, xv, hp[s], hp[s + 1], hp[s + 2]);
        hn[s + 1] = hv;
        op[off] = hv;
        __syncthreads();
        float* t = hp; hp = hn; hn = t;
        a1 = b1; a2 = b2; a3 = b3; xv = bx;
        off = offn;
    }
}

// Horizontal scan: t over W (cols), neighbor coupling along H. Thread s = row.
// Each thread streams ITS OWN row of g1/g2/g3/x in 16-float (64B) register
// chunks (gate values at (s,t) are consumed only by thread s), with one-chunk
// prefetch; output staged in registers, flushed as 4x float4 per 16 steps.
template <bool REV>
__device__ void scan_horiz(const float* __restrict__ g1, const float* __restrict__ g2,
                           const float* __restrict__ g3, const float* __restrict__ xp,
                           float* __restrict__ op, int s, float* hA, float* hB)
{
    const float* r1 = g1 + s * 224;
    const float* r2 = g2 + s * 224;
    const float* r3 = g3 + s * 224;
    const float* rx = xp + s * 224;
    float* orow = op + s * 224;

    float c1[16], c2[16], c3[16], cx[16];
    float n1[16], n2[16], n3[16], nx[16];

    auto ld = [](float* dst, const float* src, int w0) {
#pragma unroll
        for (int k = 0; k < 4; k++)
            *(float4*)&dst[4 * k] = *(const float4*)&src[w0 + 4 * k];
    };

    int w0 = REV ? 208 : 0;
    ld(c1, r1, w0); ld(c2, r2, w0); ld(c3, r3, w0); ld(cx, rx, w0);

    float* hp = hA;
    float* hn = hB;
    for (int ch = 0; ch < 14; ch++) {
        int w0n = REV ? w0 - 16 : w0 + 16;
        if (ch < 13) { ld(n1, r1, w0n); ld(n2, r2, w0n); ld(n3, r3, w0n); ld(nx, rx, w0n); }
        float ov[16];
#pragma unroll
        for (int j = 0; j < 16; j++) {
            const int k = REV ? 15 - j : j;   // compile-time after unroll
            float hv = gstep(c1[k], c2[k], c3[k], cx[k], hp[s], hp[s + 1], hp[s + 2]);
            hn[s + 1] = hv;
            ov[k] = hv;
            __syncthreads();
            float* t = hp; hp = hn; hn = t;
        }
#pragma unroll
        for (int k = 0; k < 4; k++)
            *(float4*)&orow[w0 + 4 * k] = *(float4*)&ov[4 * k];
        if (ch < 13) {
#pragma unroll
            for (int k = 0; k < 16; k++) { c1[k] = n1[k]; c2[k] = n2[k]; c3[k] = n3[k]; cx[k] = nx[k]; }
            w0 = w0n;
        }
    }
}

// One block = one (direction, batch, channel) plane. 512 blocks x 224 threads.
// d0: ylr = horizontal forward; d1: yrl = vertical reverse;
// d2: ydu = vertical forward;   d3: yud = horizontal reverse.
__global__ __launch_bounds__(224) void scan_kernel(const float* __restrict__ gates,
                                                   const float* __restrict__ x,
                                                   float* __restrict__ dout)
{
    __shared__ float hA[226];
    __shared__ float hB[226];
    int bid = blockIdx.x;
    int d = bid >> 7;
    int b = (bid >> 5) & 3;
    int c = bid & 31;
    int s = threadIdx.x;

    hA[s + 1] = 0.f;
    if (s == 0) { hA[0] = 0.f; hA[225] = 0.f; hB[0] = 0.f; hB[225] = 0.f; }
    __syncthreads();

    const float* g1 = gates + (size_t)(b * 384 + (3 * d) * 32 + c) * HW2;
    const float* g2 = g1 + 32 * (size_t)HW2;
    const float* g3 = g2 + 32 * (size_t)HW2;
    const float* xp = x + (size_t)(b * 32 + c) * HW2;
    float* op = dout + (size_t)d * NPLANE + (size_t)(b * 32 + c) * HW2;

    if (d == 0)      scan_horiz<false>(g1, g2, g3, xp, op, s, hA, hB);
    else if (d == 1) scan_vert<true >(g1, g2, g3, xp, op, s, hA, hB);
    else if (d == 2) scan_vert<false>(g1, g2, g3, xp, op, s, hA, hB);
    else             scan_horiz<true >(g1, g2, g3, xp, op, s, hA, hB);
}

// ---------------------------------------------------------------------------
// Elementwise max over the 4 direction buffers
// ---------------------------------------------------------------------------
__global__ __launch_bounds__(256) void max4_kernel(const float* __restrict__ D,
                                                   float* __restrict__ o)
{
    const int NP4 = NPLANE / 4;
    int idx = blockIdx.x * 256 + threadIdx.x;
    if (idx >= NP4) return;
    const float4* d0 = (const float4*)D;
    const float4* d1 = d0 + NP4;
    const float4* d2 = d1 + NP4;
    const float4* d3 = d2 + NP4;
    float4 a = d0[idx], b = d1[idx], c = d2[idx], d = d3[idx];
    float4 r;
    r.x = fmaxf(fmaxf(a.x, b.x), fmaxf(c.x, d.x));
    r.y = fmaxf(fmaxf(a.y, b.y), fmaxf(c.y, d.y));
    r.z = fmaxf(fmaxf(a.z, b.z), fmaxf(c.z, d.z));
    r.w = fmaxf(fmaxf(a.w, b.w), fmaxf(c.w, d.w));
    ((float4*)o)[idx] = r;
}

// ---------------------------------------------------------------------------
// conv_end_4 (32->2, 3x3 same) fused with log_softmax over the 2 channels
// ---------------------------------------------------------------------------
__global__ __launch_bounds__(256) void conv4ls_kernel(const float* __restrict__ x,
                                                      const float* __restrict__ w4,
                                                      float* __restrict__ out)
{
    __shared__ float wsh[576];
    for (int i = threadIdx.x; i < 576; i += 256) wsh[i] = w4[i];
    __syncthreads();
    int idx = blockIdx.x * 256 + threadIdx.x;
    if (idx >= 4 * HW2) return;
    int w = idx % 224;
    int h = (idx / 224) % 224;
    int b = idx / HW2;
    const float* xb = x + (size_t)b * 32 * HW2;
    float acc0 = 0.f, acc1 = 0.f;
    for (int ci = 0; ci < 32; ci++) {
        const float* xc = xb + ci * HW2;
#pragma unroll
        for (int kh = 0; kh < 3; kh++) {
            int hy = h + kh - 1;
            if (hy < 0 || hy > 223) continue;
#pragma unroll
            for (int kw = 0; kw < 3; kw++) {
                int wy = w + kw - 1;
                if (wy < 0 || wy > 223) continue;
                float v = xc[hy * 224 + wy];
                acc0 += v * wsh[(ci * 3 + kh) * 3 + kw];
                acc1 += v * wsh[288 + (ci * 3 + kh) * 3 + kw];
            }
        }
    }
    // log_softmax over {acc0, acc1}
    float m = fmaxf(acc0, acc1);
    float l = m + logf(expf(acc0 - m) + expf(acc1 - m));
    out[(size_t)(b * 2) * HW2 + h * 224 + w]     = acc0 - l;
    out[(size_t)(b * 2 + 1) * HW2 + h * 224 + w] = acc1 - l;
}

// ---------------------------------------------------------------------------
extern "C" void kernel_launch(void* const* d_in, const int* in_sizes, int n_in,
                              void* d_out, int out_size, void* d_ws, size_t ws_size,
                              hipStream_t stream)
{
    const float* gates = (const float*)d_in[0];  // [4,384,224,224]
    const float* y     = (const float*)d_in[1];  // [4,2,224,224]
    const float* w3    = (const float*)d_in[2];  // [32,2,3,3]
    const float* w4    = (const float*)d_in[3];  // [2,32,3,3]
    float* out = (float*)d_out;                  // [4,2,224,224]
    float* ws  = (float*)d_ws;

    float* y32 = ws;                 // NPLANE floats; reused as y1 / max buffer
    float* D   = ws + NPLANE;        // 4 * NPLANE floats (direction outputs)

    // y32 = conv3(y)
    conv3_kernel<<<NPLANE / 256, 256, 0, stream>>>(y, w3, y32);
    // pass 1: 4 directional scans
    scan_kernel<<<512, 224, 0, stream>>>(gates, y32, D);
    // y1 = max of 4 directions (into y32 buffer; y32 is dead)
    max4_kernel<<<NPLANE / 4 / 256, 256, 0, stream>>>(D, y32);
    // pass 2
    scan_kernel<<<512, 224, 0, stream>>>(gates, y32, D);
    max4_kernel<<<NPLANE / 4 / 256, 256, 0, stream>>>(D, y32);
    // conv4 + log_softmax
    conv4ls_kernel<<<(4 * HW2) / 256, 256, 0, stream>>>(y32, w4, out);
}